// Round 10
// baseline (281.329 us; speedup 1.0000x reference)
//
#include <hip/hip_runtime.h>
#include <hip/hip_fp16.h>

// GCN 2-layer: out = S·relu(S·(x·W1)+b1)·W2 + b2, S = D^-1/2 (A+I) D^-1/2
// R10: xw1 rewritten with MFMA f16 (W1 in registers, no LDS loop); nt loads
// reverted in agg (CSR stream is L2-hot); scanb fused into colscan via
// last-block finalize. Sort pipeline otherwise unchanged.

constexpr int BKT_BITS = 8;
constexpr int BKT = 1 << BKT_BITS;   // nodes per bucket
constexpr int EPB = 8192;            // edges per binning block

typedef _Float16 f16x8 __attribute__((ext_vector_type(8)));
typedef float f32x4 __attribute__((ext_vector_type(4)));

// ---- fused: x@W1 via MFMA (blocks [0,xw1b)) + dst histogram (rest) --------
__global__ __launch_bounds__(256) void k_pre(
    const float* __restrict__ x, const float* __restrict__ W1,
    float* __restrict__ h1pre, int n,
    const int* __restrict__ dst, int* __restrict__ hist, int ne, int nb,
    int xw1b, int* __restrict__ donecnt) {
  if (blockIdx.x == 0 && threadIdx.x == 0) *donecnt = 0;
  if ((int)blockIdx.x >= xw1b) {
    // ---------------- histogram path ----------------
    __shared__ int sh[512];
    int hb = blockIdx.x - xw1b;
    for (int i = threadIdx.x; i < nb; i += 256) sh[i] = 0;
    __syncthreads();
    int base = hb * EPB;
    int end = min(base + EPB, ne);
    for (int e = base + threadIdx.x; e < end; e += 256)
      atomicAdd(&sh[dst[e] >> BKT_BITS], 1);
    __syncthreads();
    for (int i = threadIdx.x; i < nb; i += 256) hist[hb * nb + i] = sh[i];
    return;
  }
  // ---------------- MFMA x@W1 path ----------------
  int lane = threadIdx.x & 63;
  int j16 = lane & 15;            // col for B/D, row for A
  int kh = lane >> 4;             // 0..3
  // B fragments: wf[kb][i] = W1[kb*32 + kh*8 + i][j16]   (64 VGPRs)
  f16x8 wf[16];
#pragma unroll
  for (int kb = 0; kb < 16; ++kb) {
    f16x8 w;
#pragma unroll
    for (int i = 0; i < 8; ++i)
      w[i] = (_Float16)W1[(kb * 32 + kh * 8 + i) * 16 + j16];
    wf[kb] = w;
  }
  int tiles = (n + 15) >> 4;
  int wid = (blockIdx.x * 256 + threadIdx.x) >> 6;   // global wave id = tile
  if (wid >= tiles) return;
  int tile16 = wid << 4;
  int arow = tile16 + j16;                            // A row (lane&15)
  if (arow >= n) arow = n - 1;                        // clamp (unused rows)
  const float4* x4 = (const float4*)x;
  long rb = (long)arow * 128 + kh * 2;                // float4 units
  f32x4 acc = {0.f, 0.f, 0.f, 0.f};
#pragma unroll
  for (int kb = 0; kb < 16; ++kb) {
    float4 a0 = x4[rb + kb * 8];
    float4 a1 = x4[rb + kb * 8 + 1];
    f16x8 af;
    af[0] = (_Float16)a0.x; af[1] = (_Float16)a0.y;
    af[2] = (_Float16)a0.z; af[3] = (_Float16)a0.w;
    af[4] = (_Float16)a1.x; af[5] = (_Float16)a1.y;
    af[6] = (_Float16)a1.z; af[7] = (_Float16)a1.w;
    acc = __builtin_amdgcn_mfma_f32_16x16x32_f16(af, wf[kb], acc, 0, 0, 0);
  }
  // D[i][j]: j = lane&15, i = (lane>>4)*4 + r
  int i0 = tile16 + kh * 4;
#pragma unroll
  for (int r = 0; r < 4; ++r) {
    int row = i0 + r;
    if (row < n) h1pre[(long)row * 16 + j16] = acc[r];
  }
}

// ---- pass 2: per-bucket scan over blocks; last block finalizes bstart -----
__global__ __launch_bounds__(256) void k_colscan(
    const int* __restrict__ hist, int* __restrict__ basep,
    int* __restrict__ colsum, int* __restrict__ bstart,
    int* __restrict__ donecnt, int nblk, int nb) {
  __shared__ int sh[256];
  __shared__ int carry_s;
  __shared__ int is_last;
  int k = blockIdx.x;
  int t = threadIdx.x;
  if (t == 0) carry_s = 0;
  __syncthreads();
  for (int c0 = 0; c0 < nblk; c0 += 256) {
    int b = c0 + t;
    int v = (b < nblk) ? hist[b * nb + k] : 0;
    sh[t] = v;
    __syncthreads();
    for (int d = 1; d < 256; d <<= 1) {
      int u = (t >= d) ? sh[t - d] : 0;
      __syncthreads();
      sh[t] += u;
      __syncthreads();
    }
    if (b < nblk) basep[b * nb + k] = carry_s + sh[t] - v;
    __syncthreads();
    if (t == 0) carry_s += sh[255];
    __syncthreads();
  }
  if (t == 0) atomicExch(&colsum[k], carry_s);
  __threadfence();
  if (t == 0) {
    int ticket = atomicAdd(donecnt, 1);
    is_last = (ticket == (int)gridDim.x - 1);
  }
  __syncthreads();
  if (!is_last) return;
  // ---- finalize: exclusive scan of colsum -> bstart (single block) ----
  __threadfence();
  if (t == 0) carry_s = 0;
  __syncthreads();
  for (int c0 = 0; c0 < nb; c0 += 256) {
    int kk = c0 + t;
    int v = (kk < nb) ? atomicAdd(&colsum[kk], 0) : 0;
    sh[t] = v;
    __syncthreads();
    for (int d = 1; d < 256; d <<= 1) {
      int u = (t >= d) ? sh[t - d] : 0;
      __syncthreads();
      sh[t] += u;
      __syncthreads();
    }
    if (kk < nb) bstart[kk] = carry_s + sh[t] - v;
    __syncthreads();
    if (t == 0) carry_s += sh[255];
    __syncthreads();
  }
  if (t == 0) bstart[nb] = carry_s;
}

// ---- pass 3: scatter records to bucket-contiguous array -------------------
__global__ __launch_bounds__(256) void k_binfill(
    const int* __restrict__ ei, const float* __restrict__ ew,
    const int* __restrict__ basep, const int* __restrict__ bstart,
    uint2* __restrict__ recs, int ne, int nb) {
  extern __shared__ int cur[];
  for (int i = threadIdx.x; i < nb; i += 256)
    cur[i] = basep[blockIdx.x * nb + i] + bstart[i];
  __syncthreads();
  int bs = blockIdx.x * EPB;
  int end = min(bs + EPB, ne);
  for (int e = bs + threadIdx.x; e < end; e += 256) {
    int s = ei[e];
    int d = ei[ne + e];
    float w = ew[e];
    int bkt = d >> BKT_BITS;
    int pos = atomicAdd(&cur[bkt], 1);
    recs[pos] = make_uint2((unsigned)s | ((unsigned)(d & (BKT - 1)) << 20),
                           __float_as_uint(w));
  }
}

// ---- pass 4: bucket -> per-node CSR + rowptr + dinv + f16 table -----------
__global__ __launch_bounds__(256) void k_csr(
    const uint2* __restrict__ recs, const int* __restrict__ bstart,
    uint2* __restrict__ csr, int* __restrict__ rowptr,
    float* __restrict__ dinv, const float* __restrict__ h1pre,
    __half2* __restrict__ hp16, int n, int ne) {
  __shared__ float sdeg[BKT];
  __shared__ int soff[BKT];
  __shared__ int scur[BKT];
  int t = threadIdx.x;
  sdeg[t] = 0.f;
  soff[t] = 0;
  __syncthreads();
  int k = blockIdx.x;
  int s0 = bstart[k], s1 = bstart[k + 1];
  for (int e = s0 + t; e < s1; e += 256) {
    uint2 r = recs[e];
    int dl = (r.x >> 20) & (BKT - 1);
    atomicAdd(&soff[dl], 1);
    atomicAdd(&sdeg[dl], __uint_as_float(r.y));
  }
  __syncthreads();
  int v = soff[t];
  for (int d = 1; d < BKT; d <<= 1) {
    int u = (t >= d) ? soff[t - d] : 0;
    __syncthreads();
    soff[t] += u;
    __syncthreads();
  }
  int excl = soff[t] - v;
  scur[t] = excl;
  int node = (k << BKT_BITS) + t;
  float dvv = 0.f;
  if (node < n) {
    dvv = 1.0f / sqrtf(sdeg[t] + 1.0f);
    rowptr[node] = s0 + excl;
    dinv[node] = dvv;
  }
  sdeg[t] = dvv;                 // reuse: per-node dinv for the table loop
  if (k == 0 && t == 0) rowptr[n] = ne;
  __syncthreads();
  for (int e = s0 + t; e < s1; e += 256) {
    uint2 r = recs[e];
    int dl = (r.x >> 20) & (BKT - 1);
    int pos = s0 + atomicAdd(&scur[dl], 1);
    csr[pos] = make_uint2(r.x & 0xFFFFF, r.y);
  }
  // fused: hp16[node][:] = f16(dinv[node] * h1pre[node][:])  (coalesced)
  int nbase = k << BKT_BITS;
  int nn = min(n - nbase, BKT);
  if (nn > 0) {
    const float2* hf2 = (const float2*)h1pre + (long)nbase * 8;
    __half2* hp2 = hp16 + (long)nbase * 8;
    int lim2 = nn * 8;
    for (int i = t; i < lim2; i += 256) {
      float dv2 = sdeg[i >> 3];
      float2 hv = hf2[i];
      hp2[i] = __floats2half2_rn(hv.x * dv2, hv.y * dv2);
    }
  }
}

// ---- node-major gather-aggregate over CSR (4 lanes/node, f16 table) -------
// hin8 = f16 table viewed as 8B units (4 per node row).
// MODE 1: outv (uint2*/half2 pairs) <- f16(dv*relu(v + b1))
// MODE 2: outv (float*) <- v @ W2 + b2
template <int MODE>
__global__ __launch_bounds__(256) void k_agg(
    const uint2* __restrict__ hin8, const uint2* __restrict__ csr,
    const int* __restrict__ rowptr, const float* __restrict__ dinv,
    const float* __restrict__ bias, const float* __restrict__ W2,
    void* __restrict__ outv, int n) {
  __shared__ float W2s[MODE == 2 ? 16 * 64 : 1];
  __shared__ float accs[MODE == 2 ? 64 * 16 : 1];
  if (MODE == 2) {
#pragma unroll
    for (int s = 0; s < 4; ++s) W2s[threadIdx.x + s * 256] = W2[threadIdx.x + s * 256];
  }
  int gtid = blockIdx.x * 256 + threadIdx.x;
  int node = gtid >> 2, q = gtid & 3;
  bool valid = node < n;
  float4 acc = make_float4(0.f, 0.f, 0.f, 0.f);
  float dv = 0.f;
  if (valid) {
    dv = dinv[node];
    {
      uint2 u = hin8[node * 4 + q];
      float2 f0 = __half22float2(*(const __half2*)&u.x);
      float2 f1 = __half22float2(*(const __half2*)&u.y);
      acc = make_float4(f0.x, f0.y, f1.x, f1.y);   // self term h'[node]
    }
    int e = rowptr[node], e1 = rowptr[node + 1];
    for (; e + 3 < e1; e += 4) {
      uint2 r0 = csr[e], r1 = csr[e + 1], r2 = csr[e + 2], r3 = csr[e + 3];
      uint2 g0 = hin8[r0.x * 4 + q];
      uint2 g1 = hin8[r1.x * 4 + q];
      uint2 g2 = hin8[r2.x * 4 + q];
      uint2 g3 = hin8[r3.x * 4 + q];
      float w0 = __uint_as_float(r0.y), w1 = __uint_as_float(r1.y);
      float w2 = __uint_as_float(r2.y), w3 = __uint_as_float(r3.y);
      float2 a0 = __half22float2(*(const __half2*)&g0.x);
      float2 b0 = __half22float2(*(const __half2*)&g0.y);
      float2 a1 = __half22float2(*(const __half2*)&g1.x);
      float2 b1v = __half22float2(*(const __half2*)&g1.y);
      float2 a2 = __half22float2(*(const __half2*)&g2.x);
      float2 b2v = __half22float2(*(const __half2*)&g2.y);
      float2 a3 = __half22float2(*(const __half2*)&g3.x);
      float2 b3 = __half22float2(*(const __half2*)&g3.y);
      acc.x = fmaf(w0, a0.x, acc.x); acc.y = fmaf(w0, a0.y, acc.y);
      acc.z = fmaf(w0, b0.x, acc.z); acc.w = fmaf(w0, b0.y, acc.w);
      acc.x = fmaf(w1, a1.x, acc.x); acc.y = fmaf(w1, a1.y, acc.y);
      acc.z = fmaf(w1, b1v.x, acc.z); acc.w = fmaf(w1, b1v.y, acc.w);
      acc.x = fmaf(w2, a2.x, acc.x); acc.y = fmaf(w2, a2.y, acc.y);
      acc.z = fmaf(w2, b2v.x, acc.z); acc.w = fmaf(w2, b2v.y, acc.w);
      acc.x = fmaf(w3, a3.x, acc.x); acc.y = fmaf(w3, a3.y, acc.y);
      acc.z = fmaf(w3, b3.x, acc.z); acc.w = fmaf(w3, b3.y, acc.w);
    }
    for (; e < e1; ++e) {
      uint2 r = csr[e];
      uint2 g = hin8[r.x * 4 + q];
      float w = __uint_as_float(r.y);
      float2 f0 = __half22float2(*(const __half2*)&g.x);
      float2 f1 = __half22float2(*(const __half2*)&g.y);
      acc.x = fmaf(w, f0.x, acc.x);
      acc.y = fmaf(w, f0.y, acc.y);
      acc.z = fmaf(w, f1.x, acc.z);
      acc.w = fmaf(w, f1.y, acc.w);
    }
    acc.x *= dv; acc.y *= dv; acc.z *= dv; acc.w *= dv;   // v = dv*acc
  }
  if (MODE == 1) {
    if (valid) {
      float4 b = ((const float4*)bias)[q];
      __half2 lo = __floats2half2_rn(dv * fmaxf(acc.x + b.x, 0.f),
                                     dv * fmaxf(acc.y + b.y, 0.f));
      __half2 hi = __floats2half2_rn(dv * fmaxf(acc.z + b.z, 0.f),
                                     dv * fmaxf(acc.w + b.w, 0.f));
      uint2 o;
      o.x = *(const unsigned*)&lo;
      o.y = *(const unsigned*)&hi;
      ((uint2*)outv)[node * 4 + q] = o;
    }
    return;
  }
  // MODE 2: LDS-staged 16x64 W2 epilogue (64 nodes per block)
  ((float4*)accs)[threadIdx.x] = acc;
  __syncthreads();
  const float4* W2s4 = (const float4*)W2s;
  float* out = (float*)outv;
#pragma unroll
  for (int it = 0; it < 4; ++it) {
    int nl = it * 16 + (threadIdx.x >> 4);
    int o4 = threadIdx.x & 15;
    int node2 = blockIdx.x * 64 + nl;
    if (node2 < n) {
      float4 v = ((const float4*)bias)[o4];
#pragma unroll
      for (int jj = 0; jj < 16; ++jj) {
        float a = accs[nl * 16 + jj];
        float4 w = W2s4[jj * 16 + o4];
        v.x = fmaf(a, w.x, v.x);
        v.y = fmaf(a, w.y, v.y);
        v.z = fmaf(a, w.z, v.z);
        v.w = fmaf(a, w.w, v.w);
      }
      ((float4*)out)[(long)node2 * 16 + o4] = v;
    }
  }
}

extern "C" void kernel_launch(void* const* d_in, const int* in_sizes, int n_in,
                              void* d_out, int out_size, void* d_ws, size_t ws_size,
                              hipStream_t stream) {
  const float* x  = (const float*)d_in[0];
  const int*   ei = (const int*)d_in[1];
  const float* ew = (const float*)d_in[2];
  const float* W1 = (const float*)d_in[3];
  const float* b1 = (const float*)d_in[4];
  const float* W2 = (const float*)d_in[5];
  const float* b2 = (const float*)d_in[6];
  float* out = (float*)d_out;
  int n  = in_sizes[0] / 512;
  int ne = in_sizes[1] / 2;

  int nb   = (n + BKT - 1) >> BKT_BITS;      // buckets (391)
  int nblk = (ne + EPB - 1) / EPB;           // binning blocks (391)

  char* ws = (char*)d_ws;
  size_t off = 0;
  auto alloc = [&](size_t bytes) {
    size_t r = off;
    off += (bytes + 255) & ~(size_t)255;
    return r;
  };
  float*   dinv    = (float*)  (ws + alloc((size_t)n * 4));
  float*   h1pre   = (float*)  (ws + alloc((size_t)n * 16 * 4));
  __half2* hp16    = (__half2*)(ws + alloc((size_t)n * 16 * 2));
  __half2* h1p16   = (__half2*)(ws + alloc((size_t)n * 16 * 2));
  uint2*   recs    = (uint2*)  (ws + alloc((size_t)ne * 8));
  uint2*   csr     = (uint2*)  (ws + alloc((size_t)ne * 8));
  int*     rowptr  = (int*)    (ws + alloc((size_t)(n + 1) * 4));
  int*     hist    = (int*)    (ws + alloc((size_t)nblk * nb * 4));
  int*     basep   = (int*)    (ws + alloc((size_t)nblk * nb * 4));
  int*     colsum  = (int*)    (ws + alloc((size_t)nb * 4));
  int*     bstart  = (int*)    (ws + alloc((size_t)(nb + 1) * 4));
  int*     donecnt = (int*)    (ws + alloc(4));
  (void)ws_size; (void)n_in; (void)out_size;

  int tiles = (n + 15) / 16;
  int xw1b = (tiles + 3) / 4;                // 4 waves (tiles) per block
  k_pre<<<xw1b + nblk, 256, 0, stream>>>(x, W1, h1pre, n, ei + ne, hist, ne, nb,
                                         xw1b, donecnt);

  k_colscan<<<nb, 256, 0, stream>>>(hist, basep, colsum, bstart, donecnt, nblk, nb);
  size_t shb = (size_t)nb * 4;
  k_binfill<<<nblk, 256, shb, stream>>>(ei, ew, basep, bstart, recs, ne, nb);
  k_csr<<<nb, 256, 0, stream>>>(recs, bstart, csr, rowptr, dinv, h1pre, hp16, n, ne);

  int gN4 = (n * 4 + 255) / 256;
  k_agg<1><<<gN4, 256, 0, stream>>>((const uint2*)hp16, csr, rowptr, dinv, b1,
                                    nullptr, h1p16, n);
  k_agg<2><<<gN4, 256, 0, stream>>>((const uint2*)h1p16, csr, rowptr, dinv, b2,
                                    W2, out, n);
}